// Round 16
// baseline (219.189 us; speedup 1.0000x reference)
//
#include <hip/hip_runtime.h>
#include <hip/hip_bf16.h>
#include <hip/hip_fp16.h>
#include <math.h>

// ---------------------------------------------------------------------------
// LorentzAssignment on MI355X.
//   0. cvt_count: Wq/Wk/Wa -> fp16 (24 blocks) + per-src edge counts (rest).
//   0b. gumbel_pre: g[n,d] = -log(-log(uniform(threefry(0, n*128+d)))) fp32.
//   1. gemm3: grid (blocks, 3); blockIdx.y = pass. Each block: 64-row X tile
//      (fp32->fp16 LDS), FULL 128-col W stage, 1 MFMA sweep, 2 barriers.
//        y=0: q = lorentz(x@Wq^T) fp16 narrow-negated
//        y=1: k = lorentz(x@Wk^T) fp16
//        y=2: logmap0 in-place, ass = softmax(.@Wa^T) fp16
//   2. scan1/2/3 CSR offsets; csr_fill scatters dst into segment order.
//   3. node_fused: ONE WAVE PER NODE, 4 edge-slots; closed-form softmax
//      w = 1/(x+sqrt(x^2-1)); xor-butterfly combine; gumbel epilogue reads
//      precomputed g (2 dims/lane).
// ---------------------------------------------------------------------------

#define D128 128
#define XP 136                    // padded fp16 row length (272B, %16==0)

typedef _Float16 f16x2 __attribute__((ext_vector_type(2)));
typedef _Float16 f16x8 __attribute__((ext_vector_type(8)));
typedef float f32x4 __attribute__((ext_vector_type(4)));

union U4 { uint4 u; f16x2 f2[4]; __half2 hh[4]; };

__device__ __forceinline__ void threefry2x32(unsigned x0, unsigned x1,
                                             unsigned& o0, unsigned& o1) {
  const unsigned k0 = 0u, k1 = 42u;
  const unsigned k2 = 0x1BD11BDAu ^ k0 ^ k1;
  x0 += k0; x1 += k1;
#define TF_ROT(r) { x0 += x1; x1 = (x1 << (r)) | (x1 >> (32 - (r))); x1 ^= x0; }
  TF_ROT(13) TF_ROT(15) TF_ROT(26) TF_ROT(6)
  x0 += k1; x1 += k2 + 1u;
  TF_ROT(17) TF_ROT(29) TF_ROT(16) TF_ROT(24)
  x0 += k2; x1 += k0 + 2u;
  TF_ROT(13) TF_ROT(15) TF_ROT(26) TF_ROT(6)
  x0 += k0; x1 += k1 + 3u;
  TF_ROT(17) TF_ROT(29) TF_ROT(16) TF_ROT(24)
  x0 += k1; x1 += k2 + 4u;
  TF_ROT(13) TF_ROT(15) TF_ROT(26) TF_ROT(6)
  x0 += k2; x1 += k0 + 5u;
#undef TF_ROT
  o0 = x0; o1 = x1;
}

// blocks [0,24): W fp32->fp16. blocks [24,...): per-src edge counts.
__global__ __launch_bounds__(256) void cvt_count_kernel(
    const float* __restrict__ Wq, const float* __restrict__ Wk,
    const float* __restrict__ Wa, __half* __restrict__ wqh,
    __half* __restrict__ wkh, __half* __restrict__ wah,
    const int* __restrict__ src, int* __restrict__ counts, int E) {
  int b = blockIdx.x;
  if (b < 24) {
    int i = b * 256 + threadIdx.x;
    int w = i >> 11, r = i & 2047;
    if (w >= 3) return;
    size_t off = (size_t)r * 8;
    const float* s = (w == 0) ? Wq : (w == 1) ? Wk : Wa;
    __half* d = (w == 0) ? wqh : (w == 1) ? wkh : wah;
    float4 a = *reinterpret_cast<const float4*>(s + off);
    float4 c = *reinterpret_cast<const float4*>(s + off + 4);
    union { __half2 h2[4]; uint4 u; } pk;
    pk.h2[0] = __floats2half2_rn(a.x, a.y);
    pk.h2[1] = __floats2half2_rn(a.z, a.w);
    pk.h2[2] = __floats2half2_rn(c.x, c.y);
    pk.h2[3] = __floats2half2_rn(c.z, c.w);
    *reinterpret_cast<uint4*>(d + off) = pk.u;
  } else {
    int e = (b - 24) * 256 + threadIdx.x;
    if (e < E) atomicAdd(&counts[src[e]], 1);
  }
}

// precompute gumbel noise g = -log(-log(u)), fp32, 2 dims per thread.
__global__ __launch_bounds__(256) void gumbel_pre_kernel(float* __restrict__ gmb,
                                                         int total2) {
  int i = blockIdx.x * 256 + threadIdx.x;
  int stride = gridDim.x * 256;
  for (; i < total2; i += stride) {
    unsigned idx = (unsigned)(i * 2);
    float2 r;
    {
      unsigned o0, o1;
      threefry2x32(0u, idx, o0, o1);
      unsigned bits = o0 ^ o1;
      float f = __uint_as_float((bits >> 9) | 0x3f800000u) - 1.0f;
      float u = fmaxf(1e-10f, f * (1.0f - 1e-10f) + 1e-10f);
      r.x = -logf(-logf(u));
    }
    {
      unsigned o0, o1;
      threefry2x32(0u, idx + 1u, o0, o1);
      unsigned bits = o0 ^ o1;
      float f = __uint_as_float((bits >> 9) | 0x3f800000u) - 1.0f;
      float u = fmaxf(1e-10f, f * (1.0f - 1e-10f) + 1e-10f);
      r.y = -logf(-logf(u));
    }
    *reinterpret_cast<float2*>(gmb + idx) = r;
  }
}

// grid (blocks, 3): blockIdx.y = pass (0:q, 1:k, 2:ass). 64-row X tile,
// full 128-col W stage, 2 barriers (3 for pass 2).
__global__ __launch_bounds__(256) void gemm3_kernel(
    const float* __restrict__ X, const __half* __restrict__ wqh_g,
    const __half* __restrict__ wkh_g, const __half* __restrict__ wah_g,
    const float* __restrict__ lsq, const float* __restrict__ lsk,
    __half* __restrict__ qout, __half* __restrict__ kout,
    __half* __restrict__ aout, int N) {
  __shared__ __align__(16) _Float16 xs[64 * XP];    // 17408 B
  __shared__ __align__(16) _Float16 wh[128 * XP];   // 34816 B

  const int t = threadIdx.x;
  const int row0 = blockIdx.x * 64;
  const int pass = blockIdx.y;

  // stage X fp32 -> fp16 LDS (64 rows)
#pragma unroll
  for (int i = 0; i < 8; ++i) {
    int f = t + 256 * i, r = f >> 5, c4 = f & 31;
    float4 v = make_float4(0.f, 0.f, 0.f, 0.f);
    if (row0 + r < N)
      v = *reinterpret_cast<const float4*>(X + (size_t)(row0 + r) * D128 + c4 * 4);
    union { _Float16 h[4]; uint2 u; } p;
    p.h[0] = (_Float16)v.x; p.h[1] = (_Float16)v.y;
    p.h[2] = (_Float16)v.z; p.h[3] = (_Float16)v.w;
    *reinterpret_cast<uint2*>(&xs[r * XP + c4 * 4]) = p.u;
  }

  const int w = t >> 6, lane = t & 63;
  const int lc = lane & 15;
  const int arow = 16 * w + lc;
  const int koff = (lane >> 4) * 8;
  const __half* Wg = (pass == 0) ? wqh_g : (pass == 1) ? wkh_g : wah_g;

  if (pass == 2) {
    __syncthreads();   // xs fully staged
    // logmap0 in place on xs: 2 sweeps of 32 rows
#pragma unroll
    for (int rr = 0; rr < 2; ++rr) {
      int r = (t >> 3) + 32 * rr, tr = t & 7;
      U4 c0, c1;
      c0.u = *reinterpret_cast<uint4*>(&xs[r * XP + tr * 16]);
      c1.u = *reinterpret_cast<uint4*>(&xs[r * XP + tr * 16 + 8]);
      float v[16];
      float ss = 0.f;
#pragma unroll
      for (int j = 0; j < 4; ++j) {
        float2 f = __half22float2(c0.hh[j]);
        v[2 * j] = f.x; v[2 * j + 1] = f.y; ss += f.x * f.x + f.y * f.y;
      }
#pragma unroll
      for (int j = 0; j < 4; ++j) {
        float2 f = __half22float2(c1.hh[j]);
        v[8 + 2 * j] = f.x; v[9 + 2 * j] = f.y; ss += f.x * f.x + f.y * f.y;
      }
      if (tr == 0) ss -= v[0] * v[0];
#pragma unroll
      for (int msk = 1; msk < 8; msk <<= 1) ss += __shfl_xor(ss, msk);
      float x0v = __shfl(v[0], (t & 63) & ~7);
      float dd = acoshf(fmaxf(x0v, 1.f + 1e-6f));
      float sc = dd / fmaxf(sqrtf(ss), 1e-8f);
#pragma unroll
      for (int j = 0; j < 16; ++j) v[j] *= sc;
      if (tr == 0) v[0] = 0.f;
      union { __half2 h2[4]; uint4 u; } pk;
#pragma unroll
      for (int j = 0; j < 4; ++j) pk.h2[j] = __floats2half2_rn(v[2 * j], v[2 * j + 1]);
      *reinterpret_cast<uint4*>(&xs[r * XP + tr * 16]) = pk.u;
#pragma unroll
      for (int j = 0; j < 4; ++j) pk.h2[j] = __floats2half2_rn(v[8 + 2 * j], v[9 + 2 * j]);
      *reinterpret_cast<uint4*>(&xs[r * XP + tr * 16 + 8]) = pk.u;
    }
  }

  // stage full W (128 rows fp16)
#pragma unroll
  for (int i = 0; i < 8; ++i) {
    int f = t + 256 * i, wr = f >> 4, c8 = f & 15;
    *reinterpret_cast<uint4*>(&wh[wr * XP + c8 * 8]) =
        *reinterpret_cast<const uint4*>(Wg + (size_t)wr * D128 + c8 * 8);
  }
  __syncthreads();

  f32x4 acc[8];
#pragma unroll
  for (int i = 0; i < 8; ++i) acc[i] = (f32x4){0.f, 0.f, 0.f, 0.f};
#pragma unroll
  for (int kk = 0; kk < 4; ++kk) {
    f16x8 a = *reinterpret_cast<f16x8*>(&xs[arow * XP + kk * 32 + koff]);
#pragma unroll
    for (int tt = 0; tt < 8; ++tt) {
      f16x8 b = *reinterpret_cast<f16x8*>(&wh[(tt * 16 + lc) * XP + kk * 32 + koff]);
      acc[tt] = __builtin_amdgcn_mfma_f32_16x16x32_f16(a, b, acc[tt], 0, 0, 0);
    }
  }

  if (pass < 2) {
    float scale = expf(pass ? lsk[0] : lsq[0]);
    __half* outp = pass ? kout : qout;
    float sgn = pass ? 1.f : -1.f;
#pragma unroll
    for (int j = 0; j < 4; ++j) {
      int gr = row0 + 16 * w + ((lane >> 4) << 2) + j;
      float ss = 0.f;
#pragma unroll
      for (int ct = 0; ct < 8; ++ct) {
        float v = acc[ct][j];
        if (ct == 0 && lc == 0) v = 0.f;
        ss += v * v;
      }
#pragma unroll
      for (int msk = 1; msk < 16; msk <<= 1) ss += __shfl_xor(ss, msk);
      float y0 = __shfl(acc[0][j], lane & ~15);
      float tm = scale / (1.f + expf(-y0)) + 1.1f;
      float qs = sqrtf((tm * tm - 1.f) / fmaxf(ss, 1e-8f)) * sgn;
      if (gr < N) {
#pragma unroll
        for (int ct = 0; ct < 8; ++ct) {
          float val = acc[ct][j] * qs;
          if (ct == 0 && lc == 0) val = tm;
          outp[(size_t)gr * D128 + ct * 16 + lc] = __float2half(val);
        }
      }
    }
  } else {
#pragma unroll
    for (int j = 0; j < 4; ++j) {
      int gr = row0 + 16 * w + ((lane >> 4) << 2) + j;
      float mx = acc[0][j];
#pragma unroll
      for (int ct = 1; ct < 8; ++ct) mx = fmaxf(mx, acc[ct][j]);
#pragma unroll
      for (int msk = 1; msk < 16; msk <<= 1) mx = fmaxf(mx, __shfl_xor(mx, msk));
      float e[8], sm = 0.f;
#pragma unroll
      for (int ct = 0; ct < 8; ++ct) { e[ct] = expf(acc[ct][j] - mx); sm += e[ct]; }
#pragma unroll
      for (int msk = 1; msk < 16; msk <<= 1) sm += __shfl_xor(sm, msk);
      float inv = 1.f / sm;
      if (gr < N) {
#pragma unroll
        for (int ct = 0; ct < 8; ++ct)
          aout[(size_t)gr * D128 + ct * 16 + lc] = __float2half(e[ct] * inv);
      }
    }
  }
}

// --- 3-kernel exclusive scan of counts -> start, cursor ---
__global__ __launch_bounds__(256) void scan1_kernel(const int* __restrict__ counts,
                                                    int* __restrict__ incl,
                                                    int* __restrict__ partials, int N) {
  int i = blockIdx.x * 256 + threadIdx.x;
  int c = (i < N) ? counts[i] : 0;
  int lane = threadIdx.x & 63, w = threadIdx.x >> 6;
  int v = c;
#pragma unroll
  for (int d = 1; d < 64; d <<= 1) {
    int tv = __shfl_up(v, d);
    if (lane >= d) v += tv;
  }
  __shared__ int wsum[4];
  if (lane == 63) wsum[w] = v;
  __syncthreads();
  int add = 0;
  for (int j = 0; j < w; ++j) add += wsum[j];
  v += add;
  if (i < N) incl[i] = v;
  if (threadIdx.x == 255) partials[blockIdx.x] = v;
}

__global__ __launch_bounds__(256) void scan2_kernel(int* __restrict__ partials, int nparts) {
  int t = threadIdx.x;
  int p = (t < nparts) ? partials[t] : 0;
  int lane = t & 63, w = t >> 6;
  int v = p;
#pragma unroll
  for (int d = 1; d < 64; d <<= 1) {
    int tv = __shfl_up(v, d);
    if (lane >= d) v += tv;
  }
  __shared__ int wsum[4];
  if (lane == 63) wsum[w] = v;
  __syncthreads();
  int add = 0;
  for (int j = 0; j < w; ++j) add += wsum[j];
  v += add;
  if (t < nparts) partials[t] = v - p;
}

__global__ __launch_bounds__(256) void scan3_kernel(const int* __restrict__ counts,
                                                    int* __restrict__ incl_to_start,
                                                    int* __restrict__ cursor,
                                                    const int* __restrict__ partials, int N) {
  int i = blockIdx.x * 256 + threadIdx.x;
  if (i < N) {
    int s = incl_to_start[i] - counts[i] + partials[blockIdx.x];
    incl_to_start[i] = s;
    cursor[i] = s;
  }
}

// scatter dst into CSR (segment-sorted) order
__global__ __launch_bounds__(256) void csr_fill_kernel(
    const int* __restrict__ src, const int* __restrict__ dst,
    int* __restrict__ cursor, int* __restrict__ dst_s, int E) {
  int e = blockIdx.x * 256 + threadIdx.x;
  if (e < E) {
    int pos = atomicAdd(&cursor[src[e]], 1);
    dst_s[pos] = dst[e];
  }
}

// ONE WAVE PER NODE: group g (lanes 16g..16g+15) processes edges g, g+4, ...
// closed-form softmax weight; xor-16/32 butterfly combine; gumbel epilogue
// reads precomputed g (2 dims/lane).
__global__ __launch_bounds__(256) void node_fused_kernel(
    const __half* __restrict__ qh, const __half* __restrict__ kh,
    const __half* __restrict__ ass, const float* __restrict__ gmb,
    const int* __restrict__ start, const int* __restrict__ counts,
    const int* __restrict__ dst_s, float* __restrict__ out, int N) {
  int n = blockIdx.x * 4 + (threadIdx.x >> 6);
  if (n >= N) return;
  int lane = threadIdx.x & 63;
  int g = lane >> 4, lq = lane & 15;
  int c8 = lq * 8;
  int st = start[n], deg = counts[n];

  U4 qv;
  qv.u = *reinterpret_cast<const uint4*>(qh + (size_t)n * D128 + c8);

  float lsum = 0.f;
  float acc[8];
#pragma unroll
  for (int j = 0; j < 8; ++j) acc[j] = 0.f;

  if (deg > 0) {
    int ecur = g;
    int dcur = dst_s[st + (ecur < deg ? ecur : 0)];
    U4 kv, av;
    kv.u = *reinterpret_cast<const uint4*>(kh + (size_t)dcur * D128 + c8);
    av.u = *reinterpret_cast<const uint4*>(ass + (size_t)dcur * D128 + c8);
    int nIter = (deg + 3) >> 2;

    for (int i = 0; i < nIter; ++i) {
      int enext = ecur + 4;
      int dnext = dst_s[st + (enext < deg ? enext : 0)];
      U4 kvn, avn;
      kvn.u = *reinterpret_cast<const uint4*>(kh + (size_t)dnext * D128 + c8);
      avn.u = *reinterpret_cast<const uint4*>(ass + (size_t)dnext * D128 + c8);

      float pa = __builtin_amdgcn_fdot2(qv.f2[0], kv.f2[0],
                 __builtin_amdgcn_fdot2(qv.f2[1], kv.f2[1], 0.f, false), false);
      float pb = __builtin_amdgcn_fdot2(qv.f2[2], kv.f2[2],
                 __builtin_amdgcn_fdot2(qv.f2[3], kv.f2[3], 0.f, false), false);
      float part = pa + pb;
#pragma unroll
      for (int msk = 1; msk < 16; msk <<= 1) part += __shfl_xor(part, msk);

      // w = exp(-acosh(x)) = 1/(x + sqrt(x^2-1)), x clipped to 1+1e-6
      float x = fmaxf(part, 1.f + 1e-6f);
      float tt = x + sqrtf(__builtin_fmaf(x, x, -1.f));
      float w = __builtin_amdgcn_rcpf(tt);
      if (ecur >= deg) w = 0.f;

      lsum += w;
#pragma unroll
      for (int j = 0; j < 4; ++j) {
        acc[2 * j]     = fmaf(w, (float)av.f2[j][0], acc[2 * j]);
        acc[2 * j + 1] = fmaf(w, (float)av.f2[j][1], acc[2 * j + 1]);
      }

      kv = kvn; av = avn;
      ecur = enext;
    }
  }

  // combine the 4 edge-slot groups: xor butterfly over lane bits 4,5
#pragma unroll
  for (int j = 0; j < 8; ++j) {
    acc[j] += __shfl_xor(acc[j], 16);
    acc[j] += __shfl_xor(acc[j], 32);
  }
  lsum += __shfl_xor(lsum, 16);
  lsum += __shfl_xor(lsum, 32);

  float inv = (deg > 0) ? 1.f / fmaxf(lsum, 1e-8f) : 0.f;

  // gumbel epilogue: lane handles dims (c8 + 2g, c8 + 2g + 1); g precomputed
  float2 g2 = *reinterpret_cast<const float2*>(gmb + (size_t)n * D128 + c8 + 2 * g);
  float vg0 = (logf(acc[2 * g] * inv + 1e-6f) + g2.x) / 0.2f;
  float vg1 = (logf(acc[2 * g + 1] * inv + 1e-6f) + g2.y) / 0.2f;

  float mm = fmaxf(vg0, vg1);
#pragma unroll
  for (int msk = 1; msk < 64; msk <<= 1) mm = fmaxf(mm, __shfl_xor(mm, msk));
  float e0 = expf(vg0 - mm), e1 = expf(vg1 - mm);
  float sm = e0 + e1;
#pragma unroll
  for (int msk = 1; msk < 64; msk <<= 1) sm += __shfl_xor(sm, msk);
  float invs = 1.f / sm;
  *reinterpret_cast<float2*>(out + (size_t)n * D128 + c8 + 2 * g) =
      make_float2(e0 * invs, e1 * invs);
}

extern "C" void kernel_launch(void* const* d_in, const int* in_sizes, int n_in,
                              void* d_out, int out_size, void* d_ws, size_t ws_size,
                              hipStream_t stream) {
  const float* x   = (const float*)d_in[0];
  const int*   src = (const int*)d_in[1];
  const int*   dst = (const int*)d_in[2];
  // d_in[3] = edge_value (unused by reference)
  const float* Wq  = (const float*)d_in[4];
  const float* Wk  = (const float*)d_in[5];
  const float* Wa  = (const float*)d_in[6];
  const float* lsq = (const float*)d_in[7];
  const float* lsk = (const float*)d_in[8];
  const int N = in_sizes[0] / D128;
  const int E = in_sizes[1];
  float* out = (float*)d_out;

  __half* qh   = (__half*)d_ws;
  __half* kh   = qh + (size_t)N * D128;
  __half* ah   = kh + (size_t)N * D128;
  __half* wqh  = ah + (size_t)N * D128;
  __half* wkh  = wqh + 16384;
  __half* wah  = wkh + 16384;
  float* gmb   = (float*)(wah + 16384);
  int* counts  = (int*)(gmb + (size_t)N * D128);
  int* startv  = counts + N;
  int* cursor  = startv + N;
  int* partials= cursor + N;
  int* dst_s   = partials + 256;

  hipMemsetAsync(counts, 0, (size_t)N * sizeof(int), stream);

  const int eb = (E + 255) / 256;
  cvt_count_kernel<<<24 + eb, 256, 0, stream>>>(Wq, Wk, Wa, wqh, wkh, wah,
                                                src, counts, E);
  gumbel_pre_kernel<<<2048, 256, 0, stream>>>(gmb, N * 64);

  const int gemm_blocks = (N + 63) / 64;
  gemm3_kernel<<<dim3(gemm_blocks, 3), 256, 0, stream>>>(x, wqh, wkh, wah,
                                                         lsq, lsk, qh, kh, ah, N);

  const int nb = (N + 255) / 256;
  scan1_kernel<<<nb, 256, 0, stream>>>(counts, startv, partials, N);
  scan2_kernel<<<1, 256, 0, stream>>>(partials, nb);
  scan3_kernel<<<nb, 256, 0, stream>>>(counts, startv, cursor, partials, N);
  csr_fill_kernel<<<eb, 256, 0, stream>>>(src, dst, cursor, dst_s, E);

  node_fused_kernel<<<(N + 3) / 4, 256, 0, stream>>>(qh, kh, ah, gmb, startv,
                                                     counts, dst_s, out, N);
}

// Round 20
// 206.503 us; speedup vs baseline: 1.0614x; 1.0614x over previous
//
#include <hip/hip_runtime.h>
#include <hip/hip_bf16.h>
#include <hip/hip_fp16.h>
#include <math.h>

// ---------------------------------------------------------------------------
// LorentzAssignment on MI355X.  (round-15 structure + interleaved k/ass)
//   0. cvt_count: Wq/Wk/Wa -> fp16 (24 blocks) + per-src edge counts (rest).
//   1. gemm3: ONE kernel, 64-row X tile (fp32->fp16 LDS), three W passes in
//      64-col halves (34.8KB LDS -> 4 blocks/CU).
//        Wq -> q (fp16, narrow negated), Wk -> kass[2n] (fp16),
//        logmap0 in-place, Wa -> ass = softmax -> kass[2n+1] (fp16).
//   2. scan1/2/3 CSR offsets; csr_fill scatters dst into segment order.
//   3. node_fused: ONE WAVE PER NODE, 4 edge-slots; closed-form softmax
//      w = 1/(x+sqrt(x^2-1)); per-edge k/ass rows are ADJACENT (512B span);
//      xor-butterfly combine; gumbel epilogue split across 64 lanes.
// ---------------------------------------------------------------------------

#define D128 128
#define XP 136                    // padded fp16 row length (272B, %16==0)

typedef _Float16 f16x2 __attribute__((ext_vector_type(2)));
typedef _Float16 f16x8 __attribute__((ext_vector_type(8)));
typedef float f32x4 __attribute__((ext_vector_type(4)));

union U4 { uint4 u; f16x2 f2[4]; __half2 hh[4]; };

__device__ __forceinline__ void threefry2x32(unsigned x0, unsigned x1,
                                             unsigned& o0, unsigned& o1) {
  const unsigned k0 = 0u, k1 = 42u;
  const unsigned k2 = 0x1BD11BDAu ^ k0 ^ k1;
  x0 += k0; x1 += k1;
#define TF_ROT(r) { x0 += x1; x1 = (x1 << (r)) | (x1 >> (32 - (r))); x1 ^= x0; }
  TF_ROT(13) TF_ROT(15) TF_ROT(26) TF_ROT(6)
  x0 += k1; x1 += k2 + 1u;
  TF_ROT(17) TF_ROT(29) TF_ROT(16) TF_ROT(24)
  x0 += k2; x1 += k0 + 2u;
  TF_ROT(13) TF_ROT(15) TF_ROT(26) TF_ROT(6)
  x0 += k0; x1 += k1 + 3u;
  TF_ROT(17) TF_ROT(29) TF_ROT(16) TF_ROT(24)
  x0 += k1; x1 += k2 + 4u;
  TF_ROT(13) TF_ROT(15) TF_ROT(26) TF_ROT(6)
  x0 += k2; x1 += k0 + 5u;
#undef TF_ROT
  o0 = x0; o1 = x1;
}

// blocks [0,24): W fp32->fp16. blocks [24,...): per-src edge counts.
__global__ __launch_bounds__(256) void cvt_count_kernel(
    const float* __restrict__ Wq, const float* __restrict__ Wk,
    const float* __restrict__ Wa, __half* __restrict__ wqh,
    __half* __restrict__ wkh, __half* __restrict__ wah,
    const int* __restrict__ src, int* __restrict__ counts, int E) {
  int b = blockIdx.x;
  if (b < 24) {
    int i = b * 256 + threadIdx.x;
    int w = i >> 11, r = i & 2047;
    if (w >= 3) return;
    size_t off = (size_t)r * 8;
    const float* s = (w == 0) ? Wq : (w == 1) ? Wk : Wa;
    __half* d = (w == 0) ? wqh : (w == 1) ? wkh : wah;
    float4 a = *reinterpret_cast<const float4*>(s + off);
    float4 c = *reinterpret_cast<const float4*>(s + off + 4);
    union { __half2 h2[4]; uint4 u; } pk;
    pk.h2[0] = __floats2half2_rn(a.x, a.y);
    pk.h2[1] = __floats2half2_rn(a.z, a.w);
    pk.h2[2] = __floats2half2_rn(c.x, c.y);
    pk.h2[3] = __floats2half2_rn(c.z, c.w);
    *reinterpret_cast<uint4*>(d + off) = pk.u;
  } else {
    int e = (b - 24) * 256 + threadIdx.x;
    if (e < E) atomicAdd(&counts[src[e]], 1);
  }
}

// One kernel, 64-row X tile, three W passes in 64-col halves (34.8KB LDS).
// k -> kass[2n], ass -> kass[2n+1]; q separate fp16 (narrow negated).
__global__ __launch_bounds__(256) void gemm3_kernel(
    const float* __restrict__ X, const __half* __restrict__ wqh_g,
    const __half* __restrict__ wkh_g, const __half* __restrict__ wah_g,
    const float* __restrict__ lsq, const float* __restrict__ lsk,
    __half* __restrict__ qout, __half* __restrict__ kass, int N) {
  __shared__ __align__(16) _Float16 xs[64 * XP];   // 17408 B
  __shared__ __align__(16) _Float16 wh[64 * XP];   // 17408 B

  const int t = threadIdx.x;
  const int row0 = blockIdx.x * 64;

  // stage X fp32 -> fp16 LDS (64 rows)
#pragma unroll
  for (int i = 0; i < 8; ++i) {
    int f = t + 256 * i, r = f >> 5, c4 = f & 31;
    float4 v = make_float4(0.f, 0.f, 0.f, 0.f);
    if (row0 + r < N)
      v = *reinterpret_cast<const float4*>(X + (size_t)(row0 + r) * D128 + c4 * 4);
    union { _Float16 h[4]; uint2 u; } p;
    p.h[0] = (_Float16)v.x; p.h[1] = (_Float16)v.y;
    p.h[2] = (_Float16)v.z; p.h[3] = (_Float16)v.w;
    *reinterpret_cast<uint2*>(&xs[r * XP + c4 * 4]) = p.u;
  }

  const int w = t >> 6, lane = t & 63;
  const int lc = lane & 15;
  const int arow = 16 * w + lc;
  const int koff = (lane >> 4) * 8;

  for (int m = 0; m < 3; ++m) {
    const __half* Wg = (m == 0) ? wqh_g : (m == 1) ? wkh_g : wah_g;

    if (m == 2) {
      __syncthreads();   // all MFMA reads of xs (pass 1) done
      // logmap0 in place on xs: 2 sweeps of 32 rows
#pragma unroll
      for (int rr = 0; rr < 2; ++rr) {
        int r = (t >> 3) + 32 * rr, tr = t & 7;
        U4 c0, c1;
        c0.u = *reinterpret_cast<uint4*>(&xs[r * XP + tr * 16]);
        c1.u = *reinterpret_cast<uint4*>(&xs[r * XP + tr * 16 + 8]);
        float v[16];
        float ss = 0.f;
#pragma unroll
        for (int j = 0; j < 4; ++j) {
          float2 f = __half22float2(c0.hh[j]);
          v[2 * j] = f.x; v[2 * j + 1] = f.y; ss += f.x * f.x + f.y * f.y;
        }
#pragma unroll
        for (int j = 0; j < 4; ++j) {
          float2 f = __half22float2(c1.hh[j]);
          v[8 + 2 * j] = f.x; v[9 + 2 * j] = f.y; ss += f.x * f.x + f.y * f.y;
        }
        if (tr == 0) ss -= v[0] * v[0];
#pragma unroll
        for (int msk = 1; msk < 8; msk <<= 1) ss += __shfl_xor(ss, msk);
        float x0v = __shfl(v[0], (t & 63) & ~7);
        float dd = acoshf(fmaxf(x0v, 1.f + 1e-6f));
        float sc = dd / fmaxf(sqrtf(ss), 1e-8f);
#pragma unroll
        for (int j = 0; j < 16; ++j) v[j] *= sc;
        if (tr == 0) v[0] = 0.f;
        union { __half2 h2[4]; uint4 u; } pk;
#pragma unroll
        for (int j = 0; j < 4; ++j) pk.h2[j] = __floats2half2_rn(v[2 * j], v[2 * j + 1]);
        *reinterpret_cast<uint4*>(&xs[r * XP + tr * 16]) = pk.u;
#pragma unroll
        for (int j = 0; j < 4; ++j) pk.h2[j] = __floats2half2_rn(v[8 + 2 * j], v[9 + 2 * j]);
        *reinterpret_cast<uint4*>(&xs[r * XP + tr * 16 + 8]) = pk.u;
      }
    }

    f32x4 acc[8];
#pragma unroll
    for (int i = 0; i < 8; ++i) acc[i] = (f32x4){0.f, 0.f, 0.f, 0.f};

    for (int h = 0; h < 2; ++h) {
      __syncthreads();   // xs writes done (first); prev MFMA done with wh
#pragma unroll
      for (int i = 0; i < 4; ++i) {
        int f = t + 256 * i, wr = f >> 4, c8 = f & 15;
        *reinterpret_cast<uint4*>(&wh[wr * XP + c8 * 8]) =
            *reinterpret_cast<const uint4*>(Wg + (size_t)(64 * h + wr) * D128 + c8 * 8);
      }
      __syncthreads();

#pragma unroll
      for (int kk = 0; kk < 4; ++kk) {
        f16x8 a = *reinterpret_cast<f16x8*>(&xs[arow * XP + kk * 32 + koff]);
#pragma unroll
        for (int tt = 0; tt < 4; ++tt) {
          f16x8 b = *reinterpret_cast<f16x8*>(&wh[(tt * 16 + lc) * XP + kk * 32 + koff]);
          acc[h * 4 + tt] =
              __builtin_amdgcn_mfma_f32_16x16x32_f16(a, b, acc[h * 4 + tt], 0, 0, 0);
        }
      }
    }

    if (m < 2) {
      float scale = expf(m ? lsk[0] : lsq[0]);
      float sgn = m ? 1.f : -1.f;
#pragma unroll
      for (int j = 0; j < 4; ++j) {
        int gr = row0 + 16 * w + ((lane >> 4) << 2) + j;
        float ss = 0.f;
#pragma unroll
        for (int ct = 0; ct < 8; ++ct) {
          float v = acc[ct][j];
          if (ct == 0 && lc == 0) v = 0.f;
          ss += v * v;
        }
#pragma unroll
        for (int msk = 1; msk < 16; msk <<= 1) ss += __shfl_xor(ss, msk);
        float y0 = __shfl(acc[0][j], lane & ~15);
        float tm = scale / (1.f + expf(-y0)) + 1.1f;
        float qs = sqrtf((tm * tm - 1.f) / fmaxf(ss, 1e-8f)) * sgn;
        if (gr < N) {
          __half* outp = m ? (kass + (size_t)(2 * gr) * D128)
                           : (qout + (size_t)gr * D128);
#pragma unroll
          for (int ct = 0; ct < 8; ++ct) {
            float val = acc[ct][j] * qs;
            if (ct == 0 && lc == 0) val = tm;
            outp[ct * 16 + lc] = __float2half(val);
          }
        }
      }
    } else {
#pragma unroll
      for (int j = 0; j < 4; ++j) {
        int gr = row0 + 16 * w + ((lane >> 4) << 2) + j;
        float mx = acc[0][j];
#pragma unroll
        for (int ct = 1; ct < 8; ++ct) mx = fmaxf(mx, acc[ct][j]);
#pragma unroll
        for (int msk = 1; msk < 16; msk <<= 1) mx = fmaxf(mx, __shfl_xor(mx, msk));
        float e[8], sm = 0.f;
#pragma unroll
        for (int ct = 0; ct < 8; ++ct) { e[ct] = expf(acc[ct][j] - mx); sm += e[ct]; }
#pragma unroll
        for (int msk = 1; msk < 16; msk <<= 1) sm += __shfl_xor(sm, msk);
        float inv = 1.f / sm;
        if (gr < N) {
          __half* outp = kass + (size_t)(2 * gr + 1) * D128;
#pragma unroll
          for (int ct = 0; ct < 8; ++ct)
            outp[ct * 16 + lc] = __float2half(e[ct] * inv);
        }
      }
    }
  }
}

// --- 3-kernel exclusive scan of counts -> start, cursor ---
__global__ __launch_bounds__(256) void scan1_kernel(const int* __restrict__ counts,
                                                    int* __restrict__ incl,
                                                    int* __restrict__ partials, int N) {
  int i = blockIdx.x * 256 + threadIdx.x;
  int c = (i < N) ? counts[i] : 0;
  int lane = threadIdx.x & 63, w = threadIdx.x >> 6;
  int v = c;
#pragma unroll
  for (int d = 1; d < 64; d <<= 1) {
    int tv = __shfl_up(v, d);
    if (lane >= d) v += tv;
  }
  __shared__ int wsum[4];
  if (lane == 63) wsum[w] = v;
  __syncthreads();
  int add = 0;
  for (int j = 0; j < w; ++j) add += wsum[j];
  v += add;
  if (i < N) incl[i] = v;
  if (threadIdx.x == 255) partials[blockIdx.x] = v;
}

__global__ __launch_bounds__(256) void scan2_kernel(int* __restrict__ partials, int nparts) {
  int t = threadIdx.x;
  int p = (t < nparts) ? partials[t] : 0;
  int lane = t & 63, w = t >> 6;
  int v = p;
#pragma unroll
  for (int d = 1; d < 64; d <<= 1) {
    int tv = __shfl_up(v, d);
    if (lane >= d) v += tv;
  }
  __shared__ int wsum[4];
  if (lane == 63) wsum[w] = v;
  __syncthreads();
  int add = 0;
  for (int j = 0; j < w; ++j) add += wsum[j];
  v += add;
  if (t < nparts) partials[t] = v - p;
}

__global__ __launch_bounds__(256) void scan3_kernel(const int* __restrict__ counts,
                                                    int* __restrict__ incl_to_start,
                                                    int* __restrict__ cursor,
                                                    const int* __restrict__ partials, int N) {
  int i = blockIdx.x * 256 + threadIdx.x;
  if (i < N) {
    int s = incl_to_start[i] - counts[i] + partials[blockIdx.x];
    incl_to_start[i] = s;
    cursor[i] = s;
  }
}

// scatter dst into CSR (segment-sorted) order
__global__ __launch_bounds__(256) void csr_fill_kernel(
    const int* __restrict__ src, const int* __restrict__ dst,
    int* __restrict__ cursor, int* __restrict__ dst_s, int E) {
  int e = blockIdx.x * 256 + threadIdx.x;
  if (e < E) {
    int pos = atomicAdd(&cursor[src[e]], 1);
    dst_s[pos] = dst[e];
  }
}

// ONE WAVE PER NODE: group g (lanes 16g..16g+15) processes edges g, g+4, ...
// k/ass rows adjacent in kass (512B span per edge); closed-form softmax
// weight; xor-16/32 butterfly combine; gumbel epilogue 2 dims/lane.
__global__ __launch_bounds__(256) void node_fused_kernel(
    const __half* __restrict__ qh, const __half* __restrict__ kass,
    const int* __restrict__ start, const int* __restrict__ counts,
    const int* __restrict__ dst_s, float* __restrict__ out, int N) {
  int n = blockIdx.x * 4 + (threadIdx.x >> 6);
  if (n >= N) return;
  int lane = threadIdx.x & 63;
  int g = lane >> 4, lq = lane & 15;
  int c8 = lq * 8;
  int st = start[n], deg = counts[n];

  U4 qv;
  qv.u = *reinterpret_cast<const uint4*>(qh + (size_t)n * D128 + c8);

  float lsum = 0.f;
  float acc[8];
#pragma unroll
  for (int j = 0; j < 8; ++j) acc[j] = 0.f;

  if (deg > 0) {
    int ecur = g;
    int dcur = dst_s[st + (ecur < deg ? ecur : 0)];
    U4 kv, av;
    kv.u = *reinterpret_cast<const uint4*>(kass + (size_t)(2 * dcur) * D128 + c8);
    av.u = *reinterpret_cast<const uint4*>(kass + (size_t)(2 * dcur + 1) * D128 + c8);
    int nIter = (deg + 3) >> 2;

    for (int i = 0; i < nIter; ++i) {
      int enext = ecur + 4;
      int dnext = dst_s[st + (enext < deg ? enext : 0)];
      U4 kvn, avn;
      kvn.u = *reinterpret_cast<const uint4*>(kass + (size_t)(2 * dnext) * D128 + c8);
      avn.u = *reinterpret_cast<const uint4*>(kass + (size_t)(2 * dnext + 1) * D128 + c8);

      float pa = __builtin_amdgcn_fdot2(qv.f2[0], kv.f2[0],
                 __builtin_amdgcn_fdot2(qv.f2[1], kv.f2[1], 0.f, false), false);
      float pb = __builtin_amdgcn_fdot2(qv.f2[2], kv.f2[2],
                 __builtin_amdgcn_fdot2(qv.f2[3], kv.f2[3], 0.f, false), false);
      float part = pa + pb;
#pragma unroll
      for (int msk = 1; msk < 16; msk <<= 1) part += __shfl_xor(part, msk);

      // w = exp(-acosh(x)) = 1/(x + sqrt(x^2-1)), x clipped to 1+1e-6
      float x = fmaxf(part, 1.f + 1e-6f);
      float tt = x + sqrtf(__builtin_fmaf(x, x, -1.f));
      float w = __builtin_amdgcn_rcpf(tt);
      if (ecur >= deg) w = 0.f;

      lsum += w;
#pragma unroll
      for (int j = 0; j < 4; ++j) {
        acc[2 * j]     = fmaf(w, (float)av.f2[j][0], acc[2 * j]);
        acc[2 * j + 1] = fmaf(w, (float)av.f2[j][1], acc[2 * j + 1]);
      }

      kv = kvn; av = avn;
      ecur = enext;
    }
  }

  // combine the 4 edge-slot groups: xor butterfly over lane bits 4,5
#pragma unroll
  for (int j = 0; j < 8; ++j) {
    acc[j] += __shfl_xor(acc[j], 16);
    acc[j] += __shfl_xor(acc[j], 32);
  }
  lsum += __shfl_xor(lsum, 16);
  lsum += __shfl_xor(lsum, 32);

  float inv = (deg > 0) ? 1.f / fmaxf(lsum, 1e-8f) : 0.f;

  // gumbel epilogue: lane handles dims (c8 + 2g, c8 + 2g + 1)
  float vg[2];
#pragma unroll
  for (int jj = 0; jj < 2; ++jj) {
    int j = 2 * g + jj;
    unsigned o0, o1;
    threefry2x32(0u, (unsigned)(n * D128 + c8 + j), o0, o1);
    unsigned bits = o0 ^ o1;
    float f = __uint_as_float((bits >> 9) | 0x3f800000u) - 1.0f;
    float u = fmaxf(1e-10f, f * (1.0f - 1e-10f) + 1e-10f);
    float gmb = -logf(-logf(u));
    vg[jj] = (logf(acc[j] * inv + 1e-6f) + gmb) / 0.2f;
  }
  float mm = fmaxf(vg[0], vg[1]);
#pragma unroll
  for (int msk = 1; msk < 64; msk <<= 1) mm = fmaxf(mm, __shfl_xor(mm, msk));
  float e0 = expf(vg[0] - mm), e1 = expf(vg[1] - mm);
  float sm = e0 + e1;
#pragma unroll
  for (int msk = 1; msk < 64; msk <<= 1) sm += __shfl_xor(sm, msk);
  float invs = 1.f / sm;
  *reinterpret_cast<float2*>(out + (size_t)n * D128 + c8 + 2 * g) =
      make_float2(e0 * invs, e1 * invs);
}

extern "C" void kernel_launch(void* const* d_in, const int* in_sizes, int n_in,
                              void* d_out, int out_size, void* d_ws, size_t ws_size,
                              hipStream_t stream) {
  const float* x   = (const float*)d_in[0];
  const int*   src = (const int*)d_in[1];
  const int*   dst = (const int*)d_in[2];
  // d_in[3] = edge_value (unused by reference)
  const float* Wq  = (const float*)d_in[4];
  const float* Wk  = (const float*)d_in[5];
  const float* Wa  = (const float*)d_in[6];
  const float* lsq = (const float*)d_in[7];
  const float* lsk = (const float*)d_in[8];
  const int N = in_sizes[0] / D128;
  const int E = in_sizes[1];
  float* out = (float*)d_out;

  __half* qh   = (__half*)d_ws;
  __half* kass = qh + (size_t)N * D128;            // 2N rows of 128
  __half* wqh  = kass + (size_t)2 * N * D128;
  __half* wkh  = wqh + 16384;
  __half* wah  = wkh + 16384;
  int* counts  = (int*)(wah + 16384);
  int* startv  = counts + N;
  int* cursor  = startv + N;
  int* partials= cursor + N;
  int* dst_s   = partials + 256;

  hipMemsetAsync(counts, 0, (size_t)N * sizeof(int), stream);

  const int eb = (E + 255) / 256;
  cvt_count_kernel<<<24 + eb, 256, 0, stream>>>(Wq, Wk, Wa, wqh, wkh, wah,
                                                src, counts, E);

  const int gemm_blocks = (N + 63) / 64;
  gemm3_kernel<<<gemm_blocks, 256, 0, stream>>>(x, wqh, wkh, wah, lsq, lsk,
                                                qh, kass, N);

  const int nb = (N + 255) / 256;
  scan1_kernel<<<nb, 256, 0, stream>>>(counts, startv, partials, N);
  scan2_kernel<<<1, 256, 0, stream>>>(partials, nb);
  scan3_kernel<<<nb, 256, 0, stream>>>(counts, startv, cursor, partials, N);
  csr_fill_kernel<<<eb, 256, 0, stream>>>(src, dst, cursor, dst_s, E);

  node_fused_kernel<<<(N + 3) / 4, 256, 0, stream>>>(qh, kass, startv,
                                                     counts, dst_s, out, N);
}

// Round 21
// 195.274 us; speedup vs baseline: 1.1225x; 1.0575x over previous
//
#include <hip/hip_runtime.h>
#include <hip/hip_bf16.h>
#include <hip/hip_fp16.h>
#include <math.h>

// ---------------------------------------------------------------------------
// LorentzAssignment on MI355X.  (round-15 configuration — best measured)
//   0. cvt_count: Wq/Wk/Wa -> fp16 (24 blocks) + per-src edge counts (rest).
//   1. gemm3: ONE kernel, 64-row X tile (fp32->fp16 LDS), three W passes in
//      64-col halves (34.8KB LDS -> 4 blocks/CU).
//        Wq -> q (fp16, narrow negated), Wk -> k (fp16), logmap0 in-place,
//        Wa -> ass = softmax (fp16).
//   2. scan1/2/3 CSR offsets; csr_fill scatters dst into segment order.
//   3. node_fused: ONE WAVE PER NODE, 4 edge-slots; closed-form softmax
//      w = 1/(x+sqrt(x^2-1)); xor-butterfly combine; gumbel epilogue
//      split across all 64 lanes (2 dims/lane).
// ---------------------------------------------------------------------------

#define D128 128
#define XP 136                    // padded fp16 row length (272B, %16==0)

typedef _Float16 f16x2 __attribute__((ext_vector_type(2)));
typedef _Float16 f16x8 __attribute__((ext_vector_type(8)));
typedef float f32x4 __attribute__((ext_vector_type(4)));

union U4 { uint4 u; f16x2 f2[4]; __half2 hh[4]; };

__device__ __forceinline__ void threefry2x32(unsigned x0, unsigned x1,
                                             unsigned& o0, unsigned& o1) {
  const unsigned k0 = 0u, k1 = 42u;
  const unsigned k2 = 0x1BD11BDAu ^ k0 ^ k1;
  x0 += k0; x1 += k1;
#define TF_ROT(r) { x0 += x1; x1 = (x1 << (r)) | (x1 >> (32 - (r))); x1 ^= x0; }
  TF_ROT(13) TF_ROT(15) TF_ROT(26) TF_ROT(6)
  x0 += k1; x1 += k2 + 1u;
  TF_ROT(17) TF_ROT(29) TF_ROT(16) TF_ROT(24)
  x0 += k2; x1 += k0 + 2u;
  TF_ROT(13) TF_ROT(15) TF_ROT(26) TF_ROT(6)
  x0 += k0; x1 += k1 + 3u;
  TF_ROT(17) TF_ROT(29) TF_ROT(16) TF_ROT(24)
  x0 += k1; x1 += k2 + 4u;
  TF_ROT(13) TF_ROT(15) TF_ROT(26) TF_ROT(6)
  x0 += k2; x1 += k0 + 5u;
#undef TF_ROT
  o0 = x0; o1 = x1;
}

// blocks [0,24): W fp32->fp16. blocks [24,...): per-src edge counts.
__global__ __launch_bounds__(256) void cvt_count_kernel(
    const float* __restrict__ Wq, const float* __restrict__ Wk,
    const float* __restrict__ Wa, __half* __restrict__ wqh,
    __half* __restrict__ wkh, __half* __restrict__ wah,
    const int* __restrict__ src, int* __restrict__ counts, int E) {
  int b = blockIdx.x;
  if (b < 24) {
    int i = b * 256 + threadIdx.x;
    int w = i >> 11, r = i & 2047;
    if (w >= 3) return;
    size_t off = (size_t)r * 8;
    const float* s = (w == 0) ? Wq : (w == 1) ? Wk : Wa;
    __half* d = (w == 0) ? wqh : (w == 1) ? wkh : wah;
    float4 a = *reinterpret_cast<const float4*>(s + off);
    float4 c = *reinterpret_cast<const float4*>(s + off + 4);
    union { __half2 h2[4]; uint4 u; } pk;
    pk.h2[0] = __floats2half2_rn(a.x, a.y);
    pk.h2[1] = __floats2half2_rn(a.z, a.w);
    pk.h2[2] = __floats2half2_rn(c.x, c.y);
    pk.h2[3] = __floats2half2_rn(c.z, c.w);
    *reinterpret_cast<uint4*>(d + off) = pk.u;
  } else {
    int e = (b - 24) * 256 + threadIdx.x;
    if (e < E) atomicAdd(&counts[src[e]], 1);
  }
}

// One kernel, 64-row X tile, three W passes in 64-col halves (34.8KB LDS).
__global__ __launch_bounds__(256) void gemm3_kernel(
    const float* __restrict__ X, const __half* __restrict__ wqh_g,
    const __half* __restrict__ wkh_g, const __half* __restrict__ wah_g,
    const float* __restrict__ lsq, const float* __restrict__ lsk,
    __half* __restrict__ qout, __half* __restrict__ kout,
    __half* __restrict__ aout, int N) {
  __shared__ __align__(16) _Float16 xs[64 * XP];   // 17408 B
  __shared__ __align__(16) _Float16 wh[64 * XP];   // 17408 B

  const int t = threadIdx.x;
  const int row0 = blockIdx.x * 64;

  // stage X fp32 -> fp16 LDS (64 rows)
#pragma unroll
  for (int i = 0; i < 8; ++i) {
    int f = t + 256 * i, r = f >> 5, c4 = f & 31;
    float4 v = make_float4(0.f, 0.f, 0.f, 0.f);
    if (row0 + r < N)
      v = *reinterpret_cast<const float4*>(X + (size_t)(row0 + r) * D128 + c4 * 4);
    union { _Float16 h[4]; uint2 u; } p;
    p.h[0] = (_Float16)v.x; p.h[1] = (_Float16)v.y;
    p.h[2] = (_Float16)v.z; p.h[3] = (_Float16)v.w;
    *reinterpret_cast<uint2*>(&xs[r * XP + c4 * 4]) = p.u;
  }

  const int w = t >> 6, lane = t & 63;
  const int lc = lane & 15;
  const int arow = 16 * w + lc;
  const int koff = (lane >> 4) * 8;

  for (int m = 0; m < 3; ++m) {
    const __half* Wg = (m == 0) ? wqh_g : (m == 1) ? wkh_g : wah_g;

    if (m == 2) {
      __syncthreads();   // all MFMA reads of xs (pass 1) done
      // logmap0 in place on xs: 2 sweeps of 32 rows
#pragma unroll
      for (int rr = 0; rr < 2; ++rr) {
        int r = (t >> 3) + 32 * rr, tr = t & 7;
        U4 c0, c1;
        c0.u = *reinterpret_cast<uint4*>(&xs[r * XP + tr * 16]);
        c1.u = *reinterpret_cast<uint4*>(&xs[r * XP + tr * 16 + 8]);
        float v[16];
        float ss = 0.f;
#pragma unroll
        for (int j = 0; j < 4; ++j) {
          float2 f = __half22float2(c0.hh[j]);
          v[2 * j] = f.x; v[2 * j + 1] = f.y; ss += f.x * f.x + f.y * f.y;
        }
#pragma unroll
        for (int j = 0; j < 4; ++j) {
          float2 f = __half22float2(c1.hh[j]);
          v[8 + 2 * j] = f.x; v[9 + 2 * j] = f.y; ss += f.x * f.x + f.y * f.y;
        }
        if (tr == 0) ss -= v[0] * v[0];
#pragma unroll
        for (int msk = 1; msk < 8; msk <<= 1) ss += __shfl_xor(ss, msk);
        float x0v = __shfl(v[0], (t & 63) & ~7);
        float dd = acoshf(fmaxf(x0v, 1.f + 1e-6f));
        float sc = dd / fmaxf(sqrtf(ss), 1e-8f);
#pragma unroll
        for (int j = 0; j < 16; ++j) v[j] *= sc;
        if (tr == 0) v[0] = 0.f;
        union { __half2 h2[4]; uint4 u; } pk;
#pragma unroll
        for (int j = 0; j < 4; ++j) pk.h2[j] = __floats2half2_rn(v[2 * j], v[2 * j + 1]);
        *reinterpret_cast<uint4*>(&xs[r * XP + tr * 16]) = pk.u;
#pragma unroll
        for (int j = 0; j < 4; ++j) pk.h2[j] = __floats2half2_rn(v[8 + 2 * j], v[9 + 2 * j]);
        *reinterpret_cast<uint4*>(&xs[r * XP + tr * 16 + 8]) = pk.u;
      }
    }

    f32x4 acc[8];
#pragma unroll
    for (int i = 0; i < 8; ++i) acc[i] = (f32x4){0.f, 0.f, 0.f, 0.f};

    for (int h = 0; h < 2; ++h) {
      __syncthreads();   // xs writes done (first); prev MFMA done with wh
#pragma unroll
      for (int i = 0; i < 4; ++i) {
        int f = t + 256 * i, wr = f >> 4, c8 = f & 15;
        *reinterpret_cast<uint4*>(&wh[wr * XP + c8 * 8]) =
            *reinterpret_cast<const uint4*>(Wg + (size_t)(64 * h + wr) * D128 + c8 * 8);
      }
      __syncthreads();

#pragma unroll
      for (int kk = 0; kk < 4; ++kk) {
        f16x8 a = *reinterpret_cast<f16x8*>(&xs[arow * XP + kk * 32 + koff]);
#pragma unroll
        for (int tt = 0; tt < 4; ++tt) {
          f16x8 b = *reinterpret_cast<f16x8*>(&wh[(tt * 16 + lc) * XP + kk * 32 + koff]);
          acc[h * 4 + tt] =
              __builtin_amdgcn_mfma_f32_16x16x32_f16(a, b, acc[h * 4 + tt], 0, 0, 0);
        }
      }
    }

    if (m < 2) {
      float scale = expf(m ? lsk[0] : lsq[0]);
      __half* outp = m ? kout : qout;
      float sgn = m ? 1.f : -1.f;
#pragma unroll
      for (int j = 0; j < 4; ++j) {
        int gr = row0 + 16 * w + ((lane >> 4) << 2) + j;
        float ss = 0.f;
#pragma unroll
        for (int ct = 0; ct < 8; ++ct) {
          float v = acc[ct][j];
          if (ct == 0 && lc == 0) v = 0.f;
          ss += v * v;
        }
#pragma unroll
        for (int msk = 1; msk < 16; msk <<= 1) ss += __shfl_xor(ss, msk);
        float y0 = __shfl(acc[0][j], lane & ~15);
        float tm = scale / (1.f + expf(-y0)) + 1.1f;
        float qs = sqrtf((tm * tm - 1.f) / fmaxf(ss, 1e-8f)) * sgn;
        if (gr < N) {
#pragma unroll
          for (int ct = 0; ct < 8; ++ct) {
            float val = acc[ct][j] * qs;
            if (ct == 0 && lc == 0) val = tm;
            outp[(size_t)gr * D128 + ct * 16 + lc] = __float2half(val);
          }
        }
      }
    } else {
#pragma unroll
      for (int j = 0; j < 4; ++j) {
        int gr = row0 + 16 * w + ((lane >> 4) << 2) + j;
        float mx = acc[0][j];
#pragma unroll
        for (int ct = 1; ct < 8; ++ct) mx = fmaxf(mx, acc[ct][j]);
#pragma unroll
        for (int msk = 1; msk < 16; msk <<= 1) mx = fmaxf(mx, __shfl_xor(mx, msk));
        float e[8], sm = 0.f;
#pragma unroll
        for (int ct = 0; ct < 8; ++ct) { e[ct] = expf(acc[ct][j] - mx); sm += e[ct]; }
#pragma unroll
        for (int msk = 1; msk < 16; msk <<= 1) sm += __shfl_xor(sm, msk);
        float inv = 1.f / sm;
        if (gr < N) {
#pragma unroll
          for (int ct = 0; ct < 8; ++ct)
            aout[(size_t)gr * D128 + ct * 16 + lc] = __float2half(e[ct] * inv);
        }
      }
    }
  }
}

// --- 3-kernel exclusive scan of counts -> start, cursor ---
__global__ __launch_bounds__(256) void scan1_kernel(const int* __restrict__ counts,
                                                    int* __restrict__ incl,
                                                    int* __restrict__ partials, int N) {
  int i = blockIdx.x * 256 + threadIdx.x;
  int c = (i < N) ? counts[i] : 0;
  int lane = threadIdx.x & 63, w = threadIdx.x >> 6;
  int v = c;
#pragma unroll
  for (int d = 1; d < 64; d <<= 1) {
    int tv = __shfl_up(v, d);
    if (lane >= d) v += tv;
  }
  __shared__ int wsum[4];
  if (lane == 63) wsum[w] = v;
  __syncthreads();
  int add = 0;
  for (int j = 0; j < w; ++j) add += wsum[j];
  v += add;
  if (i < N) incl[i] = v;
  if (threadIdx.x == 255) partials[blockIdx.x] = v;
}

__global__ __launch_bounds__(256) void scan2_kernel(int* __restrict__ partials, int nparts) {
  int t = threadIdx.x;
  int p = (t < nparts) ? partials[t] : 0;
  int lane = t & 63, w = t >> 6;
  int v = p;
#pragma unroll
  for (int d = 1; d < 64; d <<= 1) {
    int tv = __shfl_up(v, d);
    if (lane >= d) v += tv;
  }
  __shared__ int wsum[4];
  if (lane == 63) wsum[w] = v;
  __syncthreads();
  int add = 0;
  for (int j = 0; j < w; ++j) add += wsum[j];
  v += add;
  if (t < nparts) partials[t] = v - p;
}

__global__ __launch_bounds__(256) void scan3_kernel(const int* __restrict__ counts,
                                                    int* __restrict__ incl_to_start,
                                                    int* __restrict__ cursor,
                                                    const int* __restrict__ partials, int N) {
  int i = blockIdx.x * 256 + threadIdx.x;
  if (i < N) {
    int s = incl_to_start[i] - counts[i] + partials[blockIdx.x];
    incl_to_start[i] = s;
    cursor[i] = s;
  }
}

// scatter dst into CSR (segment-sorted) order
__global__ __launch_bounds__(256) void csr_fill_kernel(
    const int* __restrict__ src, const int* __restrict__ dst,
    int* __restrict__ cursor, int* __restrict__ dst_s, int E) {
  int e = blockIdx.x * 256 + threadIdx.x;
  if (e < E) {
    int pos = atomicAdd(&cursor[src[e]], 1);
    dst_s[pos] = dst[e];
  }
}

// ONE WAVE PER NODE: group g (lanes 16g..16g+15) processes edges g, g+4, ...
// closed-form softmax weight; xor-16/32 butterfly combine; gumbel epilogue
// split across all 64 lanes (2 dims each).
__global__ __launch_bounds__(256) void node_fused_kernel(
    const __half* __restrict__ qh, const __half* __restrict__ kh,
    const __half* __restrict__ ass, const int* __restrict__ start,
    const int* __restrict__ counts, const int* __restrict__ dst_s,
    float* __restrict__ out, int N) {
  int n = blockIdx.x * 4 + (threadIdx.x >> 6);
  if (n >= N) return;
  int lane = threadIdx.x & 63;
  int g = lane >> 4, lq = lane & 15;
  int c8 = lq * 8;
  int st = start[n], deg = counts[n];

  U4 qv;
  qv.u = *reinterpret_cast<const uint4*>(qh + (size_t)n * D128 + c8);

  float lsum = 0.f;
  float acc[8];
#pragma unroll
  for (int j = 0; j < 8; ++j) acc[j] = 0.f;

  if (deg > 0) {
    int ecur = g;
    int dcur = dst_s[st + (ecur < deg ? ecur : 0)];
    U4 kv, av;
    kv.u = *reinterpret_cast<const uint4*>(kh + (size_t)dcur * D128 + c8);
    av.u = *reinterpret_cast<const uint4*>(ass + (size_t)dcur * D128 + c8);
    int nIter = (deg + 3) >> 2;

    for (int i = 0; i < nIter; ++i) {
      int enext = ecur + 4;
      int dnext = dst_s[st + (enext < deg ? enext : 0)];
      U4 kvn, avn;
      kvn.u = *reinterpret_cast<const uint4*>(kh + (size_t)dnext * D128 + c8);
      avn.u = *reinterpret_cast<const uint4*>(ass + (size_t)dnext * D128 + c8);

      float pa = __builtin_amdgcn_fdot2(qv.f2[0], kv.f2[0],
                 __builtin_amdgcn_fdot2(qv.f2[1], kv.f2[1], 0.f, false), false);
      float pb = __builtin_amdgcn_fdot2(qv.f2[2], kv.f2[2],
                 __builtin_amdgcn_fdot2(qv.f2[3], kv.f2[3], 0.f, false), false);
      float part = pa + pb;
#pragma unroll
      for (int msk = 1; msk < 16; msk <<= 1) part += __shfl_xor(part, msk);

      // w = exp(-acosh(x)) = 1/(x + sqrt(x^2-1)), x clipped to 1+1e-6
      float x = fmaxf(part, 1.f + 1e-6f);
      float tt = x + sqrtf(__builtin_fmaf(x, x, -1.f));
      float w = __builtin_amdgcn_rcpf(tt);
      if (ecur >= deg) w = 0.f;

      lsum += w;
#pragma unroll
      for (int j = 0; j < 4; ++j) {
        acc[2 * j]     = fmaf(w, (float)av.f2[j][0], acc[2 * j]);
        acc[2 * j + 1] = fmaf(w, (float)av.f2[j][1], acc[2 * j + 1]);
      }

      kv = kvn; av = avn;
      ecur = enext;
    }
  }

  // combine the 4 edge-slot groups: xor butterfly over lane bits 4,5
#pragma unroll
  for (int j = 0; j < 8; ++j) {
    acc[j] += __shfl_xor(acc[j], 16);
    acc[j] += __shfl_xor(acc[j], 32);
  }
  lsum += __shfl_xor(lsum, 16);
  lsum += __shfl_xor(lsum, 32);

  float inv = (deg > 0) ? 1.f / fmaxf(lsum, 1e-8f) : 0.f;

  // gumbel epilogue: lane handles dims (c8 + 2g, c8 + 2g + 1)
  float vg[2];
#pragma unroll
  for (int jj = 0; jj < 2; ++jj) {
    int j = 2 * g + jj;
    unsigned o0, o1;
    threefry2x32(0u, (unsigned)(n * D128 + c8 + j), o0, o1);
    unsigned bits = o0 ^ o1;
    float f = __uint_as_float((bits >> 9) | 0x3f800000u) - 1.0f;
    float u = fmaxf(1e-10f, f * (1.0f - 1e-10f) + 1e-10f);
    float gmb = -logf(-logf(u));
    vg[jj] = (logf(acc[j] * inv + 1e-6f) + gmb) / 0.2f;
  }
  float mm = fmaxf(vg[0], vg[1]);
#pragma unroll
  for (int msk = 1; msk < 64; msk <<= 1) mm = fmaxf(mm, __shfl_xor(mm, msk));
  float e0 = expf(vg[0] - mm), e1 = expf(vg[1] - mm);
  float sm = e0 + e1;
#pragma unroll
  for (int msk = 1; msk < 64; msk <<= 1) sm += __shfl_xor(sm, msk);
  float invs = 1.f / sm;
  *reinterpret_cast<float2*>(out + (size_t)n * D128 + c8 + 2 * g) =
      make_float2(e0 * invs, e1 * invs);
}

extern "C" void kernel_launch(void* const* d_in, const int* in_sizes, int n_in,
                              void* d_out, int out_size, void* d_ws, size_t ws_size,
                              hipStream_t stream) {
  const float* x   = (const float*)d_in[0];
  const int*   src = (const int*)d_in[1];
  const int*   dst = (const int*)d_in[2];
  // d_in[3] = edge_value (unused by reference)
  const float* Wq  = (const float*)d_in[4];
  const float* Wk  = (const float*)d_in[5];
  const float* Wa  = (const float*)d_in[6];
  const float* lsq = (const float*)d_in[7];
  const float* lsk = (const float*)d_in[8];
  const int N = in_sizes[0] / D128;
  const int E = in_sizes[1];
  float* out = (float*)d_out;

  __half* qh   = (__half*)d_ws;
  __half* kh   = qh + (size_t)N * D128;
  __half* ah   = kh + (size_t)N * D128;
  __half* wqh  = ah + (size_t)N * D128;
  __half* wkh  = wqh + 16384;
  __half* wah  = wkh + 16384;
  int* counts  = (int*)(wah + 16384);
  int* startv  = counts + N;
  int* cursor  = startv + N;
  int* partials= cursor + N;
  int* dst_s   = partials + 256;

  hipMemsetAsync(counts, 0, (size_t)N * sizeof(int), stream);

  const int eb = (E + 255) / 256;
  cvt_count_kernel<<<24 + eb, 256, 0, stream>>>(Wq, Wk, Wa, wqh, wkh, wah,
                                                src, counts, E);

  const int gemm_blocks = (N + 63) / 64;
  gemm3_kernel<<<gemm_blocks, 256, 0, stream>>>(x, wqh, wkh, wah, lsq, lsk,
                                                qh, kh, ah, N);

  const int nb = (N + 255) / 256;
  scan1_kernel<<<nb, 256, 0, stream>>>(counts, startv, partials, N);
  scan2_kernel<<<1, 256, 0, stream>>>(partials, nb);
  scan3_kernel<<<nb, 256, 0, stream>>>(counts, startv, cursor, partials, N);
  csr_fill_kernel<<<eb, 256, 0, stream>>>(src, dst, cursor, dst_s, E);

  node_fused_kernel<<<(N + 3) / 4, 256, 0, stream>>>(qh, kh, ah, startv,
                                                     counts, dst_s, out, N);
}